// Round 5
// baseline (96.719 us; speedup 1.0000x reference)
//
#include <hip/hip_runtime.h>
#include <math.h>

// Problem constants (B=8, T=1024, D=512, LEFT=16, RIGHT=0)
constexpr int Bn = 8;
constexpr int Tn = 1024;
constexpr int Dn = 512;
constexpr int BT = Bn * Tn;      // 8192 rows
constexpr int WIN = 16;

typedef short bs8 __attribute__((ext_vector_type(8)));     // 8 bf16 (bit pattern)
typedef unsigned short us8 __attribute__((ext_vector_type(8)));
typedef float fx4 __attribute__((ext_vector_type(4)));

// bf16 helpers (self-contained, RNE)
__device__ inline unsigned short f2bf(float f) {
    unsigned int u = __float_as_uint(f);
    u += 0x7FFFu + ((u >> 16) & 1u);
    return (unsigned short)(u >> 16);
}
__device__ inline float bf2f(unsigned short h) {
    return __uint_as_float(((unsigned int)h) << 16);
}

// chunk-swizzle involution: spreads ds_read banks to 2-way (free) [G4/m136]
__device__ inline int fsw(int m) { return (m & 3) ^ ((m >> 2) & 3); }

// ---------------------------------------------------------------------------
// Kernel 1 (fused prep): block-range dispatch
//   blocks [0,2048):   split X (f32) -> Ap bf16 [8192][1024] = [hi|lo]
//   blocks [2048,2304): g_partial: Gp[kc][b][a] = sum_{j in 128-chunk} M[a,j]C[b,j]
//   blocks [2304,2368): split+transpose V (hi) -> Bt rows [512,1024)
// ---------------------------------------------------------------------------
__global__ __launch_bounds__(256) void prep(
    const float* __restrict__ X,
    const float* __restrict__ Mw, const float* __restrict__ Cw,
    const float* __restrict__ Vw,
    short* __restrict__ Ap, float* __restrict__ Gp, short* __restrict__ Bt)
{
    __shared__ float smem[64 * 65];
    const int blk = blockIdx.x;
    const int tid = threadIdx.x;

    if (blk < 2048) {
        // ---- split_x ----
        const int i = blk * 256 + tid;
        const int m = i >> 6;
        const int kc = (i & 63) * 8;
        const float4* xp = (const float4*)(X + (size_t)m * Dn + kc);
        const float4 x0 = xp[0], x1 = xp[1];
        const float xs[8] = {x0.x, x0.y, x0.z, x0.w, x1.x, x1.y, x1.z, x1.w};
        union { bs8 v; unsigned short u[8]; } hi, lo;
        #pragma unroll
        for (int j = 0; j < 8; ++j) {
            const float x = xs[j];
            const unsigned short h = f2bf(x);
            hi.u[j] = h;
            lo.u[j] = f2bf(x - bf2f(h));
        }
        short* base = Ap + (size_t)m * 1024 + kc;
        *(bs8*)base         = hi.v;
        *(bs8*)(base + 512) = lo.v;
    } else if (blk < 2304) {
        // ---- g_partial: 64x64 tile, K-chunk of 128 ----
        float* As = smem;              // [64][17]
        float* Bs = smem + 64 * 17;    // [64][17]
        const int bz = blk - 2048;
        const int kch = bz >> 6;            // 0..3
        const int r6 = bz & 63;
        const int b0 = (r6 & 7) * 64;
        const int a0 = (r6 >> 3) * 64;
        const int tx = tid & 15, ty = tid >> 4;

        float acc[4][4] = {};
        for (int j0 = kch * 128; j0 < kch * 128 + 128; j0 += 16) {
            const int r = tid >> 2;
            const int c = (tid & 3) * 4;
            const float4 a = *(const float4*)(Mw + (size_t)(a0 + r) * Dn + j0 + c);
            As[r * 17 + c + 0] = a.x; As[r * 17 + c + 1] = a.y;
            As[r * 17 + c + 2] = a.z; As[r * 17 + c + 3] = a.w;
            const float4 b = *(const float4*)(Cw + (size_t)(b0 + r) * Dn + j0 + c);
            Bs[r * 17 + c + 0] = b.x; Bs[r * 17 + c + 1] = b.y;
            Bs[r * 17 + c + 2] = b.z; Bs[r * 17 + c + 3] = b.w;
            __syncthreads();
            #pragma unroll
            for (int kk = 0; kk < 16; ++kk) {
                float av[4], bv[4];
                #pragma unroll
                for (int i = 0; i < 4; ++i) av[i] = As[(ty * 4 + i) * 17 + kk];
                #pragma unroll
                for (int j = 0; j < 4; ++j) bv[j] = Bs[(tx * 4 + j) * 17 + kk];
                #pragma unroll
                for (int i = 0; i < 4; ++i)
                    #pragma unroll
                    for (int j = 0; j < 4; ++j)
                        acc[i][j] += av[i] * bv[j];
            }
            __syncthreads();
        }
        #pragma unroll
        for (int j = 0; j < 4; ++j) {
            const int b = b0 + tx * 4 + j;
            float4 col = make_float4(acc[0][j], acc[1][j], acc[2][j], acc[3][j]);
            *(float4*)(Gp + ((size_t)kch * 512 + b) * 512 + a0 + ty * 4) = col;
        }
    } else {
        // ---- split_v: Bt[512+n][k] = hi(V[k][n]) ----
        float* tile = smem;            // [64][65]
        const int z = blk - 2304;
        const int k0 = (z & 7) * 64;
        const int n0 = (z >> 3) * 64;
        #pragma unroll
        for (int rr = 0; rr < 4; ++rr) {
            const int row = (tid >> 4) * 4 + rr;
            const int col = (tid & 15) * 4;
            const float4 w = *(const float4*)(Vw + (size_t)(k0 + row) * Dn + n0 + col);
            tile[row * 65 + col + 0] = w.x; tile[row * 65 + col + 1] = w.y;
            tile[row * 65 + col + 2] = w.z; tile[row * 65 + col + 3] = w.w;
        }
        __syncthreads();
        const int n  = tid >> 2;
        const int ks = (tid & 3) * 16;
        union { bs8 v; unsigned short u[8]; } hi0, hi1;
        #pragma unroll
        for (int i = 0; i < 8; ++i) {
            hi0.u[i] = f2bf(tile[(ks + i) * 65 + n]);
            hi1.u[i] = f2bf(tile[(ks + 8 + i) * 65 + n]);
        }
        short* base = Bt + (size_t)(512 + n0 + n) * 1024 + k0 + ks;
        *(bs8*)base       = hi0.v;
        *(bs8*)(base + 8) = hi1.v;
    }
}

// ---------------------------------------------------------------------------
// Kernel 2: pack G = sum of 4 partials, split hi/lo into Bt rows [0,512):
// Bt[b][a] = hi(G[a][b]), Bt[b][512+a] = lo.
// ---------------------------------------------------------------------------
__global__ __launch_bounds__(256) void pack_g(const float* __restrict__ Gp,
                                              short* __restrict__ Bt)
{
    const int i = blockIdx.x * 256 + threadIdx.x;   // 32768 threads
    const int b = i >> 6;
    const int a8 = (i & 63) * 8;
    float s[8] = {};
    #pragma unroll
    for (int kc = 0; kc < 4; ++kc) {
        const float* p = Gp + ((size_t)kc * 512 + b) * 512 + a8;
        const float4 p0 = *(const float4*)p;
        const float4 p1 = *(const float4*)(p + 4);
        s[0] += p0.x; s[1] += p0.y; s[2] += p0.z; s[3] += p0.w;
        s[4] += p1.x; s[5] += p1.y; s[6] += p1.z; s[7] += p1.w;
    }
    union { bs8 v; unsigned short u[8]; } hi, lo;
    #pragma unroll
    for (int j = 0; j < 8; ++j) {
        const unsigned short h = f2bf(s[j]);
        hi.u[j] = h;
        lo.u[j] = f2bf(s[j] - bf2f(h));
    }
    short* base = Bt + (size_t)b * 1024 + a8;
    *(bs8*)base         = hi.v;
    *(bs8*)(base + 512) = lo.v;
}

// ---------------------------------------------------------------------------
// Kernel 3: bf16 MFMA GEMM, double-buffered, K-split for load balance.
//   Y = X@G (K'=1536) split into part0 k'[0,768) -> P0 (ws, f32)
//                     and part1 k'[768,1536) -> P1 (d_out[...,512:] scratch)
//   V' = X@V hi (K'=512) -> Vws bf16
// Grid 768 blocks (3/CU): lin<512 Y (24 K-steps), else V (16 K-steps).
// 128x128 tile, BK=32, 4 waves x (64x64), mfma_f32_16x16x32_bf16.
// ---------------------------------------------------------------------------
__global__ __launch_bounds__(256) void gemm_mfma(
    const short* __restrict__ Ap, const short* __restrict__ Bt,
    float* __restrict__ P0, float* __restrict__ P1out,
    unsigned short* __restrict__ Vws)
{
    __shared__ short Asl[2][128 * 32];   // 2 x 8 KB
    __shared__ short Bsl[2][128 * 32];

    const int lin = blockIdx.x;              // 0..767
    int mt, nt, mode, kStart, kEnd;
    if (lin < 512) {                         // Y blocks
        const int xcd = lin & 7;
        const int s   = lin >> 3;            // 0..63
        mt = xcd * 8 + (s & 7);
        const int rest = s >> 3;             // 0..7
        nt = rest & 3;
        const int part = rest >> 2;          // 0..1
        mode = part;
        kStart = part ? 768 : 0;
        kEnd   = part ? 1536 : 768;
    } else {                                 // V blocks
        const int l2 = lin - 512;
        const int xcd = l2 & 7;
        const int s   = l2 >> 3;             // 0..31
        mt = xcd * 8 + (s & 7);
        nt = 4 + (s >> 3);
        mode = 2;
        kStart = 0; kEnd = 512;
    }
    const int m0 = mt * 128, n0g = nt * 128;

    const int tid = threadIdx.x;
    const int ln  = tid & 63;
    const int wid = tid >> 6;
    const int wr = wid >> 1, wc = wid & 1;
    const int lrow = ln & 15;
    const int lkb  = ln >> 4;                          // 0..3
    const int jsw  = lkb ^ fsw(lrow);                  // swizzled chunk index

    fx4 acc[4][4] = {};

    size_t abase[2], bbase[2];
    #pragma unroll
    for (int h = 0; h < 2; ++h) {
        const int c = tid + h * 256;
        const int am = c >> 2;
        const int aj = (c & 3) ^ fsw(am);              // chunk actually staged
        abase[h] = (size_t)(m0  + am) * 1024 + aj * 8;
        bbase[h] = (size_t)(n0g + am) * 1024 + aj * 8;
    }

    auto stage = [&](int bi, int k0s) {
        const int ka0 = (k0s < 1024) ? k0s : (k0s - 1024);   // A: hi,lo,hi
        const int kb0 = (k0s < 512)  ? k0s : (k0s - 512);    // B: hi,hi,lo
        #pragma unroll
        for (int h = 0; h < 2; ++h) {
            const int c = tid + h * 256;
            __builtin_amdgcn_global_load_lds(
                (const __attribute__((address_space(1))) unsigned int*)(Ap + abase[h] + ka0),
                (__attribute__((address_space(3))) unsigned int*)(&Asl[bi][c * 8]), 16, 0, 0);
            __builtin_amdgcn_global_load_lds(
                (const __attribute__((address_space(1))) unsigned int*)(Bt + bbase[h] + kb0),
                (__attribute__((address_space(3))) unsigned int*)(&Bsl[bi][c * 8]), 16, 0, 0);
        }
    };

    auto compute = [&](const short* As_, const short* Bs_) {
        bs8 a[4], b[4];
        #pragma unroll
        for (int mf = 0; mf < 4; ++mf) {
            const int m = wr * 64 + mf * 16 + lrow;
            a[mf] = *(const bs8*)(As_ + (m * 4 + jsw) * 8);
        }
        #pragma unroll
        for (int nf = 0; nf < 4; ++nf) {
            const int n = wc * 64 + nf * 16 + lrow;
            b[nf] = *(const bs8*)(Bs_ + (n * 4 + jsw) * 8);
        }
        #pragma unroll
        for (int mf = 0; mf < 4; ++mf)
            #pragma unroll
            for (int nf = 0; nf < 4; ++nf)
                acc[mf][nf] = __builtin_amdgcn_mfma_f32_16x16x32_bf16(
                    a[mf], b[nf], acc[mf][nf], 0, 0, 0);
    };

    stage(0, kStart);
    __syncthreads();
    for (int k0 = kStart; k0 < kEnd; k0 += 64) {
        stage(1, k0 + 32);                 // k-range length is a multiple of 64
        compute(Asl[0], Bsl[0]);
        __syncthreads();
        if (k0 + 64 < kEnd) stage(0, k0 + 64);
        compute(Asl[1], Bsl[1]);
        __syncthreads();
    }

    const int colb = n0g + wc * 64;        // absolute n'
    #pragma unroll
    for (int mf = 0; mf < 4; ++mf) {
        #pragma unroll
        for (int nf = 0; nf < 4; ++nf) {
            const int col = colb + nf * 16 + lrow;
            #pragma unroll
            for (int r = 0; r < 4; ++r) {
                const int row = m0 + wr * 64 + mf * 16 + lkb * 4 + r;
                const float v = acc[mf][nf][r];
                if (mode == 0)      P0[(size_t)row * 512 + col] = v;
                else if (mode == 1) P1out[(size_t)row * 1024 + 512 + col] = v;
                else                Vws[(size_t)row * 512 + (col - 512)] = f2bf(v);
            }
        }
    }
}

// ---------------------------------------------------------------------------
// Kernel 4: windowed attention. One wave per token, XCD-swizzled block ids.
//   Y[t] = P0[t] + P1[t]; logit[t,s] = Y[t] . X[s]  (X exact f32)
//   Invalid slots (src<0): logit = 0 exactly, no V term.
// ---------------------------------------------------------------------------
__global__ __launch_bounds__(256) void attn_win(
    const float* __restrict__ X,
    const float* __restrict__ P0,
    const unsigned short* __restrict__ Vws,
    float* __restrict__ out)
{
    const int lin = blockIdx.x;                       // 0..2047
    const int swz = (lin & 7) * 256 + (lin >> 3);     // 8 XCDs x 256 blocks
    const int wid = threadIdx.x >> 6;
    const int ln  = threadIdx.x & 63;
    const int tg  = swz * 4 + wid;
    const int b   = tg >> 10;
    const int tt  = tg & 1023;

    // Y fragment = P0 + P1 (P1 lives in d_out[..., 512:1024] scratch)
    float q[8];
    {
        const float4* p0p = (const float4*)(P0 + (size_t)tg * 512);
        const float4* p1p = (const float4*)(out + (size_t)tg * 1024 + 512);
        const float4 a0 = p0p[ln * 2],     a1 = p1p[ln * 2];
        const float4 c0 = p0p[ln * 2 + 1], c1 = p1p[ln * 2 + 1];
        q[0] = a0.x + a1.x; q[1] = a0.y + a1.y; q[2] = a0.z + a1.z; q[3] = a0.w + a1.w;
        q[4] = c0.x + c1.x; q[5] = c0.y + c1.y; q[6] = c0.z + c1.z; q[7] = c0.w + c1.w;
    }

    float lw[16];
    float4 x15a, x15b;   // own X row, saved from w=15 for the concat copy
    #pragma unroll
    for (int w = 0; w < WIN; ++w) {
        const int src = tt - (WIN - 1) + w;
        float dot = 0.0f;
        if (src >= 0) {
            const float* xrow = X + (size_t)(b * Tn + src) * Dn + ln * 8;
            const float4 k0 = *(const float4*)xrow;
            const float4 k1 = *(const float4*)(xrow + 4);
            dot = q[0] * k0.x + q[1] * k0.y + q[2] * k0.z + q[3] * k0.w
                + q[4] * k1.x + q[5] * k1.y + q[6] * k1.z + q[7] * k1.w;
            if (w == WIN - 1) { x15a = k0; x15b = k1; }
        }
        #pragma unroll
        for (int st = 32; st > 0; st >>= 1) dot += __shfl_xor(dot, st, 64);
        lw[w] = (src >= 0) ? dot : 0.0f;
    }

    // Concat copy: out[..., 0:512] = X row (reuses the w=15 load)
    {
        float* o0 = out + (size_t)tg * 1024 + ln * 8;
        *(float4*)o0       = x15a;
        *(float4*)(o0 + 4) = x15b;
    }

    float mx = lw[0];
    #pragma unroll
    for (int w = 1; w < WIN; ++w) mx = fmaxf(mx, lw[w]);
    float den = 0.0f;
    float sc[16];
    #pragma unroll
    for (int w = 0; w < WIN; ++w) { sc[w] = expf(lw[w] - mx); den += sc[w]; }
    const float inv = 1.0f / den;

    float acc[8] = {};
    #pragma unroll
    for (int w = 0; w < WIN; ++w) {
        const int src = tt - (WIN - 1) + w;
        if (src >= 0) {
            const float sw = sc[w] * inv;
            const us8 v = *(const us8*)(Vws + (size_t)(b * Tn + src) * Dn + ln * 8);
            #pragma unroll
            for (int j = 0; j < 8; ++j) acc[j] += sw * bf2f(v[j]);
        }
    }

    float* o1 = out + (size_t)tg * 1024 + 512 + ln * 8;
    *(float4*)o1       = make_float4(acc[0], acc[1], acc[2], acc[3]);
    *(float4*)(o1 + 4) = make_float4(acc[4], acc[5], acc[6], acc[7]);
}

// ---------------------------------------------------------------------------
extern "C" void kernel_launch(void* const* d_in, const int* in_sizes, int n_in,
                              void* d_out, int out_size, void* d_ws, size_t ws_size,
                              hipStream_t stream)
{
    const float* X  = (const float*)d_in[0];
    const float* Mw = (const float*)d_in[1];
    const float* Cw = (const float*)d_in[2];
    const float* Vw = (const float*)d_in[3];
    float* out = (float*)d_out;

    // ws layout (46 MB total):
    short* Ap = (short*)d_ws;                                          // 16 MB
    short* Bt = Ap + (size_t)BT * 1024;                                // 2 MB
    unsigned short* Vws = (unsigned short*)(Bt + (size_t)1024 * 1024); // 8 MB
    float* Gp = (float*)(Vws + (size_t)BT * Dn);                       // 4 MB
    float* P0 = Gp + (size_t)4 * 512 * 512;                            // 16 MB

    prep<<<2368, 256, 0, stream>>>(X, Mw, Cw, Vw, Ap, Gp, Bt);
    pack_g<<<128, 256, 0, stream>>>(Gp, Bt);
    gemm_mfma<<<768, 256, 0, stream>>>(Ap, Bt, P0, out, Vws);
    attn_win<<<2048, 256, 0, stream>>>(X, P0, Vws, out);
}